// Round 11
// baseline (477.127 us; speedup 1.0000x reference)
//
#include <hip/hip_runtime.h>
#include <hip/hip_bf16.h>
#include <math.h>

#define LEAKY 0.01f
#define SCAN_BLOCK 256
#define SCAN_ITEMS 4
#define SCAN_TILE (SCAN_BLOCK * SCAN_ITEMS)  // 1024 items per block

struct __align__(8) Bf4 { __hip_bfloat16 a, b, c, d; };

__device__ __forceinline__ float bfu(unsigned short u) {
    return __uint_as_float((unsigned)u << 16);
}

__global__ void zero_i32(int* __restrict__ p, int n) {
    int i = blockIdx.x * blockDim.x + threadIdx.x;
    if (i < n) p[i] = 0;
}

// counts degree AND records each edge's rank within its row (kills fill atomic)
__global__ void count_edges(const int* __restrict__ row, int E,
                            int* __restrict__ deg, int* __restrict__ rank) {
    int i = blockIdx.x * blockDim.x + threadIdx.x;
    if (i < E) rank[i] = atomicAdd(&deg[row[i]], 1);
}

// ---- 2-phase device-wide exclusive scan of deg[N] -> row_ptr[N+1] ----
__global__ __launch_bounds__(SCAN_BLOCK) void scan_phase1(
    const int* __restrict__ deg, int* __restrict__ blocksum, int N) {
    __shared__ int red[SCAN_BLOCK];
    int b = blockIdx.x, t = threadIdx.x;
    int base = b * SCAN_TILE + t * SCAN_ITEMS;
    int s = 0;
#pragma unroll
    for (int j = 0; j < SCAN_ITEMS; j++) {
        int i = base + j;
        if (i < N) s += deg[i];
    }
    red[t] = s;
    __syncthreads();
    for (int off = SCAN_BLOCK / 2; off > 0; off >>= 1) {
        if (t < off) red[t] += red[t + off];
        __syncthreads();
    }
    if (t == 0) blocksum[b] = red[0];
}

__global__ __launch_bounds__(SCAN_BLOCK) void scan_phase3(
    const int* __restrict__ deg, const int* __restrict__ blocksum,
    int* __restrict__ row_ptr, int G, int N) {
    __shared__ int bs[SCAN_BLOCK];
    __shared__ int red[SCAN_BLOCK];
    int b = blockIdx.x, t = threadIdx.x;
    bs[t] = (t < G) ? blocksum[t] : 0;
    __syncthreads();
    for (int off = 1; off < SCAN_BLOCK; off <<= 1) {
        int v = (t >= off) ? bs[t - off] : 0;
        __syncthreads();
        bs[t] += v;
        __syncthreads();
    }
    int boff = (b == 0) ? 0 : bs[b - 1];
    if (b == 0 && t == 0) row_ptr[N] = bs[G - 1];

    int base = b * SCAN_TILE + t * SCAN_ITEMS;
    int v[SCAN_ITEMS];
    int s = 0;
#pragma unroll
    for (int j = 0; j < SCAN_ITEMS; j++) {
        int i = base + j;
        v[j] = (i < N) ? deg[i] : 0;
        s += v[j];
    }
    red[t] = s;
    __syncthreads();
    for (int off = 1; off < SCAN_BLOCK; off <<= 1) {
        int x = (t >= off) ? red[t - off] : 0;
        __syncthreads();
        red[t] += x;
        __syncthreads();
    }
    int run = boff + ((t == 0) ? 0 : red[t - 1]);
#pragma unroll
    for (int j = 0; j < SCAN_ITEMS; j++) {
        int i = base + j;
        if (i < N) { row_ptr[i] = run; run += v[j]; }
    }
}
// ----------------------------------------------------------------------

// a0 = concat(user_embed, entity_embed) (fp32) + bf16 gather copy
__global__ void build_a0(const float4* __restrict__ ue, const float4* __restrict__ ee,
                         float4* __restrict__ a0, __hip_bfloat16* __restrict__ a0b,
                         int nu4, int ntot4) {
    int i = blockIdx.x * blockDim.x + threadIdx.x;
    if (i < ntot4) {
        float4 v = (i < nu4) ? ue[i] : ee[i - nu4];
        a0[i] = v;
        Bf4 q = {__float2bfloat16(v.x), __float2bfloat16(v.y),
                 __float2bfloat16(v.z), __float2bfloat16(v.w)};
        *(Bf4*)&a0b[(size_t)i * 4] = q;
    }
}

// atomic-free CSR fill using precomputed ranks.
// csr.x = col * 128 (BYTE offset of the neighbor's row in the 128-B-stride
// bf16 table — saves a shift per edge in the hot loop); csr.y = val bits.
__global__ void fill_csr(const int* __restrict__ row, const int* __restrict__ col,
                         const float* __restrict__ val, const int* __restrict__ rank,
                         const int* __restrict__ row_ptr, int E,
                         int2* __restrict__ csr) {
    int i = blockIdx.x * blockDim.x + threadIdx.x;
    if (i < E) {
        int p = row_ptr[row[i]] + rank[i];
        csr[p] = make_int2(col[i] << 7, __float_as_int(val[i]));
    }
}

__device__ __forceinline__ void fma4(float o[4], float sv, const float4& wv) {
    o[0] = fmaf(sv, wv.x, o[0]);
    o[1] = fmaf(sv, wv.y, o[1]);
    o[2] = fmaf(sv, wv.z, o[2]);
    o[3] = fmaf(sv, wv.w, o[3]);
}

// Fused GNN layer (R7 structure, shfl-free edge loop).
// Block = 256 thr (4 waves), 8 nodes per wave, lane = dim.
// Phase 1: per 8-edge chunk, all 64 lanes BROADCAST-load the same csr[e+u]
//   (1 request, L1-hot, no ds_bpermute / lgkm stalls), then 8 independent
//   row-gathers (uniform byte offset + lane*2) pipeline in the vmcnt queue.
//   Tail: clamp index to last edge, zero the val — keeps 8-deep pipelining.
// Phase 2: register-blocked MLP, weights from global (L1/L2-resident), LDS
//   holds only S rows (stride 132, conflict-free).
template<int DOUT>
__global__ __launch_bounds__(256, 4) void gnn_layer(
    const float* __restrict__ feats, const __hip_bfloat16* __restrict__ featsb,
    const int2* __restrict__ csr, const int* __restrict__ row_ptr,
    const float* __restrict__ W1, const float* __restrict__ b1,
    const float* __restrict__ W2, const float* __restrict__ b2,
    float* __restrict__ out, __hip_bfloat16* __restrict__ outb, int N) {
    __shared__ __align__(16) float S[32 * 132];
    int wv = threadIdx.x >> 6, lane = threadIdx.x & 63;
    const char* fbb = (const char*)featsb;
    int l2 = lane << 1;
    int nb = blockIdx.x * 32 + wv * 8;  // first node of this wave

    // prefetch all row bounds for this wave's 8 nodes (independent loads)
    int rp[9];
#pragma unroll
    for (int i = 0; i <= 8; i++) {
        int idx = nb + i;
        rp[i] = row_ptr[(idx < N) ? idx : N];
    }

    // ---- phase 1: aggregate 8 nodes ----
    for (int ni = 0; ni < 8; ni++) {
        int node = nb + ni;
        if (node >= N) break;
        float x = feats[(size_t)node * 64 + lane];
        int e0 = rp[ni], e1 = rp[ni + 1];
        float acc = 0.f;
        for (int e = e0; e < e1; e += 8) {
            int last = e1 - 1;
            int2 m[8];
#pragma unroll
            for (int u = 0; u < 8; u++) {
                int ee = e + u;
                m[u] = csr[(ee < last) ? ee : last];  // broadcast load
            }
            float f[8];
#pragma unroll
            for (int u = 0; u < 8; u++)
                f[u] = bfu(*(const ushort*)(fbb + (unsigned)m[u].x + l2));
#pragma unroll
            for (int u = 0; u < 8; u++) {
                float v = (e + u < e1) ? __int_as_float(m[u].y) : 0.f;
                acc = fmaf(v, f[u], acc);
            }
        }
        float* sp = &S[(wv * 8 + ni) * 132];
        sp[lane]      = x + acc;  // s1
        sp[64 + lane] = x * acc;  // s2
    }
    __threadfence_block();  // wave-local LDS write -> cross-lane read ordering

    // ---- phase 2: MLP + epilogue ----
    if constexpr (DOUT == 64) {
        int strip = lane & 15, gg = lane >> 4;   // 16 strips x 4 dims; 4 node-pairs
        int d0 = strip * 4;
        float4 b1v = *(const float4*)&b1[d0];
        float4 b2v = *(const float4*)&b2[d0];
        float oa[4] = {b1v.x + b2v.x, b1v.y + b2v.y, b1v.z + b2v.z, b1v.w + b2v.w};
        float ob[4] = {oa[0], oa[1], oa[2], oa[3]};
        const float* spa = &S[(wv * 8 + 2 * gg) * 132];
        const float* spb = spa + 132;
#pragma unroll
        for (int half = 0; half < 2; half++) {
            const float* W  = half ? W2 : W1;
            const float* sa = spa + half * 64;
            const float* sb = spb + half * 64;
#pragma unroll 2
            for (int k = 0; k < 64; k += 4) {
                float4 va = *(const float4*)&sa[k];
                float4 vb = *(const float4*)&sb[k];
                float4 wr0 = *(const float4*)&W[(k + 0) * 64 + d0];
                float4 wr1 = *(const float4*)&W[(k + 1) * 64 + d0];
                float4 wr2 = *(const float4*)&W[(k + 2) * 64 + d0];
                float4 wr3 = *(const float4*)&W[(k + 3) * 64 + d0];
                fma4(oa, va.x, wr0); fma4(oa, va.y, wr1);
                fma4(oa, va.z, wr2); fma4(oa, va.w, wr3);
                fma4(ob, vb.x, wr0); fma4(ob, vb.y, wr1);
                fma4(ob, vb.z, wr2); fma4(ob, vb.w, wr3);
            }
        }
#pragma unroll
        for (int t = 0; t < 2; t++) {
            float* o = t ? ob : oa;
            float h0 = (o[0] > 0.f) ? o[0] : LEAKY * o[0];
            float h1 = (o[1] > 0.f) ? o[1] : LEAKY * o[1];
            float h2 = (o[2] > 0.f) ? o[2] : LEAKY * o[2];
            float h3 = (o[3] > 0.f) ? o[3] : LEAKY * o[3];
            float ss = h0 * h0 + h1 * h1 + h2 * h2 + h3 * h3;
            ss += __shfl_xor(ss, 1, 64);
            ss += __shfl_xor(ss, 2, 64);
            ss += __shfl_xor(ss, 4, 64);
            ss += __shfl_xor(ss, 8, 64);   // 16 lanes = one node
            float sc = 1.0f / fmaxf(sqrtf(ss), 1e-12f);
            int node = nb + 2 * gg + t;
            if (node < N) {
                float4 rv = {h0 * sc, h1 * sc, h2 * sc, h3 * sc};
                *(float4*)&out[(size_t)node * 64 + d0] = rv;
                Bf4 q = {__float2bfloat16(rv.x), __float2bfloat16(rv.y),
                         __float2bfloat16(rv.z), __float2bfloat16(rv.w)};
                *(Bf4*)&outb[(size_t)node * 64 + d0] = q;
            }
        }
    } else {
        int strip = lane & 7, nI = lane >> 3;    // 8 strips x 4 dims; 8 nodes
        int d0 = strip * 4;
        float4 b1v = *(const float4*)&b1[d0];
        float4 b2v = *(const float4*)&b2[d0];
        float o[4] = {b1v.x + b2v.x, b1v.y + b2v.y, b1v.z + b2v.z, b1v.w + b2v.w};
        const float* sp = &S[(wv * 8 + nI) * 132];
#pragma unroll
        for (int half = 0; half < 2; half++) {
            const float* W  = half ? W2 : W1;
            const float* sv = sp + half * 64;
#pragma unroll 2
            for (int k = 0; k < 64; k += 4) {
                float4 v   = *(const float4*)&sv[k];
                float4 wr0 = *(const float4*)&W[(k + 0) * 32 + d0];
                float4 wr1 = *(const float4*)&W[(k + 1) * 32 + d0];
                float4 wr2 = *(const float4*)&W[(k + 2) * 32 + d0];
                float4 wr3 = *(const float4*)&W[(k + 3) * 32 + d0];
                fma4(o, v.x, wr0); fma4(o, v.y, wr1);
                fma4(o, v.z, wr2); fma4(o, v.w, wr3);
            }
        }
        float h0 = (o[0] > 0.f) ? o[0] : LEAKY * o[0];
        float h1 = (o[1] > 0.f) ? o[1] : LEAKY * o[1];
        float h2 = (o[2] > 0.f) ? o[2] : LEAKY * o[2];
        float h3 = (o[3] > 0.f) ? o[3] : LEAKY * o[3];
        float ss = h0 * h0 + h1 * h1 + h2 * h2 + h3 * h3;
        ss += __shfl_xor(ss, 1, 64);
        ss += __shfl_xor(ss, 2, 64);
        ss += __shfl_xor(ss, 4, 64);       // 8 lanes = one node
        float sc = 1.0f / fmaxf(sqrtf(ss), 1e-12f);
        int node = nb + nI;
        if (node < N) {
            float4 rv = {h0 * sc, h1 * sc, h2 * sc, h3 * sc};
            *(float4*)&out[(size_t)node * 32 + d0] = rv;
        }
    }
}

// final = concat(a0, a1, a2); score[b] = dot(final[u], final[NU+i]) over 160 dims
__global__ __launch_bounds__(256) void score_pairs(
    const float* __restrict__ a0, const float* __restrict__ a1,
    const float* __restrict__ a2,
    const int* __restrict__ uid, const int* __restrict__ iid,
    float* __restrict__ out, int B, int NU) {
    int wave = threadIdx.x >> 6, lane = threadIdx.x & 63;
    int p = blockIdx.x * 4 + wave;
    if (p >= B) return;
    int u = uid[p], it = iid[p];
    size_t un = (size_t)u, in = (size_t)(NU + it);
    float s = a0[un * 64 + lane] * a0[in * 64 + lane];
    s = fmaf(a1[un * 64 + lane], a1[in * 64 + lane], s);
    if (lane < 32) s = fmaf(a2[un * 32 + lane], a2[in * 32 + lane], s);
#pragma unroll
    for (int m = 32; m >= 1; m >>= 1) s += __shfl_xor(s, m, 64);
    if (lane == 0) out[p] = s;
}

extern "C" void kernel_launch(void* const* d_in, const int* in_sizes, int n_in,
                              void* d_out, int out_size, void* d_ws, size_t ws_size,
                              hipStream_t stream) {
    const int*   edge_row  = (const int*)d_in[0];
    const int*   edge_col  = (const int*)d_in[1];
    const float* edge_vals = (const float*)d_in[2];
    const float* ue        = (const float*)d_in[3];
    const float* ee        = (const float*)d_in[4];
    const float* W1_0 = (const float*)d_in[5];
    const float* b1_0 = (const float*)d_in[6];
    const float* W2_0 = (const float*)d_in[7];
    const float* b2_0 = (const float*)d_in[8];
    const float* W1_1 = (const float*)d_in[9];
    const float* b1_1 = (const float*)d_in[10];
    const float* W2_1 = (const float*)d_in[11];
    const float* b2_1 = (const float*)d_in[12];
    const int*   uid  = (const int*)d_in[13];
    const int*   iid  = (const int*)d_in[14];
    float* out = (float*)d_out;

    const int E  = in_sizes[0];
    const int NU = in_sizes[3] / 64;
    const int NE = in_sizes[4] / 64;
    const int N  = NU + NE;
    const int B  = in_sizes[13];
    const int G  = (N + SCAN_TILE - 1) / SCAN_TILE;  // must be <= SCAN_BLOCK

    char* ws = (char*)d_ws;
    size_t off = 0;
    auto alloc = [&](size_t bytes) -> char* {
        char* p = ws + off;
        off = (off + bytes + 255) & ~(size_t)255;
        return p;
    };
    int*   deg      = (int*)alloc((size_t)N * 4);
    int*   rank     = (int*)alloc((size_t)E * 4);
    int*   row_ptr  = (int*)alloc((size_t)(N + 1) * 4);
    int*   blocksum = (int*)alloc((size_t)1024 * 4);
    int2*  csr      = (int2*)alloc((size_t)E * 8);
    float* a0       = (float*)alloc((size_t)N * 64 * 4);
    float* a1       = (float*)alloc((size_t)N * 64 * 4);
    float* a2       = (float*)alloc((size_t)N * 32 * 4);
    __hip_bfloat16* a0b = (__hip_bfloat16*)alloc((size_t)N * 64 * 2);
    __hip_bfloat16* a1b = (__hip_bfloat16*)alloc((size_t)N * 64 * 2);
    (void)ws_size; (void)n_in; (void)out_size; (void)NE;

    zero_i32<<<(N + 255) / 256, 256, 0, stream>>>(deg, N);
    count_edges<<<(E + 255) / 256, 256, 0, stream>>>(edge_row, E, deg, rank);
    scan_phase1<<<G, SCAN_BLOCK, 0, stream>>>(deg, blocksum, N);
    scan_phase3<<<G, SCAN_BLOCK, 0, stream>>>(deg, blocksum, row_ptr, G, N);
    fill_csr<<<(E + 255) / 256, 256, 0, stream>>>(edge_row, edge_col, edge_vals,
                                                  rank, row_ptr, E, csr);
    int ntot4 = N * 16, nu4 = NU * 16;
    build_a0<<<(ntot4 + 255) / 256, 256, 0, stream>>>((const float4*)ue, (const float4*)ee,
                                                      (float4*)a0, a0b, nu4, ntot4);
    gnn_layer<64><<<(N + 31) / 32, 256, 0, stream>>>(a0, a0b, csr, row_ptr,
                                                     W1_0, b1_0, W2_0, b2_0, a1, a1b, N);
    gnn_layer<32><<<(N + 31) / 32, 256, 0, stream>>>(a1, a1b, csr, row_ptr,
                                                     W1_1, b1_1, W2_1, b2_1, a2, nullptr, N);
    score_pairs<<<(B + 3) / 4, 256, 0, stream>>>(a0, a1, a2, uid, iid, out, B, NU);
}

// Round 12
// 469.571 us; speedup vs baseline: 1.0161x; 1.0161x over previous
//
#include <hip/hip_runtime.h>
#include <hip/hip_bf16.h>
#include <math.h>

#define LEAKY 0.01f
#define SCAN_BLOCK 256
#define SCAN_ITEMS 4
#define SCAN_TILE (SCAN_BLOCK * SCAN_ITEMS)  // 1024 items per block

struct __align__(8) Bf4 { __hip_bfloat16 a, b, c, d; };

__device__ __forceinline__ float bfu(unsigned short u) {
    return __uint_as_float((unsigned)u << 16);
}

__global__ void zero_i32(int* __restrict__ p, int n) {
    int i = blockIdx.x * blockDim.x + threadIdx.x;
    if (i < n) p[i] = 0;
}

// Fused: blocks [0,GC) do the degree histogram; blocks [GC,GC+GB) build
// a0 = concat(user_embed, entity_embed) fp32 + bf16 gather copy.
__global__ void count_and_build(const int* __restrict__ row, int E, int GC,
                                int* __restrict__ deg,
                                const float4* __restrict__ ue,
                                const float4* __restrict__ ee,
                                float4* __restrict__ a0,
                                __hip_bfloat16* __restrict__ a0b,
                                int nu4, int ntot4) {
    if ((int)blockIdx.x < GC) {
        int i = blockIdx.x * blockDim.x + threadIdx.x;
        if (i < E) atomicAdd(&deg[row[i]], 1);
    } else {
        int i = (blockIdx.x - GC) * blockDim.x + threadIdx.x;
        if (i < ntot4) {
            float4 v = (i < nu4) ? ue[i] : ee[i - nu4];
            a0[i] = v;
            Bf4 q = {__float2bfloat16(v.x), __float2bfloat16(v.y),
                     __float2bfloat16(v.z), __float2bfloat16(v.w)};
            *(Bf4*)&a0b[(size_t)i * 4] = q;
        }
    }
}

// ---- 2-phase device-wide exclusive scan of deg[N] -> row_ptr[N+1], cursor ----
__global__ __launch_bounds__(SCAN_BLOCK) void scan_phase1(
    const int* __restrict__ deg, int* __restrict__ blocksum, int N) {
    __shared__ int red[SCAN_BLOCK];
    int b = blockIdx.x, t = threadIdx.x;
    int base = b * SCAN_TILE + t * SCAN_ITEMS;
    int s = 0;
#pragma unroll
    for (int j = 0; j < SCAN_ITEMS; j++) {
        int i = base + j;
        if (i < N) s += deg[i];
    }
    red[t] = s;
    __syncthreads();
    for (int off = SCAN_BLOCK / 2; off > 0; off >>= 1) {
        if (t < off) red[t] += red[t + off];
        __syncthreads();
    }
    if (t == 0) blocksum[b] = red[0];
}

__global__ __launch_bounds__(SCAN_BLOCK) void scan_phase3(
    const int* __restrict__ deg, const int* __restrict__ blocksum,
    int* __restrict__ row_ptr, int* __restrict__ cursor, int G, int N) {
    __shared__ int bs[SCAN_BLOCK];
    __shared__ int red[SCAN_BLOCK];
    int b = blockIdx.x, t = threadIdx.x;
    bs[t] = (t < G) ? blocksum[t] : 0;
    __syncthreads();
    for (int off = 1; off < SCAN_BLOCK; off <<= 1) {
        int v = (t >= off) ? bs[t - off] : 0;
        __syncthreads();
        bs[t] += v;
        __syncthreads();
    }
    int boff = (b == 0) ? 0 : bs[b - 1];
    if (b == 0 && t == 0) row_ptr[N] = bs[G - 1];

    int base = b * SCAN_TILE + t * SCAN_ITEMS;
    int v[SCAN_ITEMS];
    int s = 0;
#pragma unroll
    for (int j = 0; j < SCAN_ITEMS; j++) {
        int i = base + j;
        v[j] = (i < N) ? deg[i] : 0;
        s += v[j];
    }
    red[t] = s;
    __syncthreads();
    for (int off = 1; off < SCAN_BLOCK; off <<= 1) {
        int x = (t >= off) ? red[t - off] : 0;
        __syncthreads();
        red[t] += x;
        __syncthreads();
    }
    int run = boff + ((t == 0) ? 0 : red[t - 1]);
#pragma unroll
    for (int j = 0; j < SCAN_ITEMS; j++) {
        int i = base + j;
        if (i < N) { row_ptr[i] = run; cursor[i] = run; run += v[j]; }
    }
}
// ----------------------------------------------------------------------

// cursor-atomic CSR fill (no rank array): one pass over the edge list
__global__ void fill_csr(const int* __restrict__ row, const int* __restrict__ col,
                         const float* __restrict__ val, int E,
                         int* __restrict__ cursor, int2* __restrict__ csr) {
    int i = blockIdx.x * blockDim.x + threadIdx.x;
    if (i < E) {
        int r = row[i];
        int p = atomicAdd(&cursor[r], 1);
        csr[p] = make_int2(col[i], __float_as_int(val[i]));
    }
}

__device__ __forceinline__ void fma4(float o[4], float sv, const float4& wv) {
    o[0] = fmaf(sv, wv.x, o[0]);
    o[1] = fmaf(sv, wv.y, o[1]);
    o[2] = fmaf(sv, wv.z, o[2]);
    o[3] = fmaf(sv, wv.w, o[3]);
}

// Fused GNN layer — R7's proven structure, gather depth 8 -> 16.
// Block = 256 thr (4 waves), 8 nodes per wave, lane = dim.
// Phase 1: lane-parallel CSR metadata load (one coalesced fetch for up to 64
//   edges) -> shfl-distribute -> chunks of 16 independent bf16 gathers
//   (lanes >= deg shfl col=0/val=0 -> no-op fma on hot row 0). fp32 accumulate.
// Phase 2: register-blocked MLP, weights from global (L1/L2-resident), LDS
//   holds only S rows (stride 132, conflict-free).
template<int DOUT>
__global__ __launch_bounds__(256, 4) void gnn_layer(
    const float* __restrict__ feats, const __hip_bfloat16* __restrict__ featsb,
    const int2* __restrict__ csr, const int* __restrict__ row_ptr,
    const float* __restrict__ W1, const float* __restrict__ b1,
    const float* __restrict__ W2, const float* __restrict__ b2,
    float* __restrict__ out, __hip_bfloat16* __restrict__ outb, int N) {
    __shared__ __align__(16) float S[32 * 132];
    int wv = threadIdx.x >> 6, lane = threadIdx.x & 63;
    const ushort* fb = (const ushort*)featsb;
    int nb = blockIdx.x * 32 + wv * 8;  // first node of this wave

    // ---- phase 1: aggregate 8 nodes ----
    for (int ni = 0; ni < 8; ni++) {
        int node = nb + ni;
        if (node >= N) break;
        int e0 = row_ptr[node];
        int degn = row_ptr[node + 1] - e0;
        float acc = 0.f;
        int done = 0;
        while (done < degn) {
            int take = min(64, degn - done);
            int2 m = make_int2(0, 0);
            if (lane < take) m = csr[e0 + done + lane];
            int nch = (take + 15) >> 4;
            for (int c2 = 0; c2 < nch; c2++) {
                int base = c2 * 16;
                float f[16], vv[16];
#pragma unroll
                for (int u = 0; u < 16; u++) {
                    int col = __shfl(m.x, base + u, 64);
                    vv[u] = __int_as_float(__shfl(m.y, base + u, 64));
                    f[u] = bfu(fb[(size_t)col * 64 + lane]);
                }
#pragma unroll
                for (int u = 0; u < 16; u++) acc = fmaf(vv[u], f[u], acc);
            }
            done += take;
        }
        float x = feats[(size_t)node * 64 + lane];
        float* sp = &S[(wv * 8 + ni) * 132];
        sp[lane]      = x + acc;  // s1
        sp[64 + lane] = x * acc;  // s2
    }
    __threadfence_block();  // wave-local LDS write -> cross-lane read ordering

    // ---- phase 2: MLP + epilogue ----
    if constexpr (DOUT == 64) {
        int strip = lane & 15, gg = lane >> 4;   // 16 strips x 4 dims; 4 node-pairs
        int d0 = strip * 4;
        float4 b1v = *(const float4*)&b1[d0];
        float4 b2v = *(const float4*)&b2[d0];
        float oa[4] = {b1v.x + b2v.x, b1v.y + b2v.y, b1v.z + b2v.z, b1v.w + b2v.w};
        float ob[4] = {oa[0], oa[1], oa[2], oa[3]};
        const float* spa = &S[(wv * 8 + 2 * gg) * 132];
        const float* spb = spa + 132;
#pragma unroll
        for (int half = 0; half < 2; half++) {
            const float* W  = half ? W2 : W1;
            const float* sa = spa + half * 64;
            const float* sb = spb + half * 64;
#pragma unroll 2
            for (int k = 0; k < 64; k += 4) {
                float4 va = *(const float4*)&sa[k];
                float4 vb = *(const float4*)&sb[k];
                float4 wr0 = *(const float4*)&W[(k + 0) * 64 + d0];
                float4 wr1 = *(const float4*)&W[(k + 1) * 64 + d0];
                float4 wr2 = *(const float4*)&W[(k + 2) * 64 + d0];
                float4 wr3 = *(const float4*)&W[(k + 3) * 64 + d0];
                fma4(oa, va.x, wr0); fma4(oa, va.y, wr1);
                fma4(oa, va.z, wr2); fma4(oa, va.w, wr3);
                fma4(ob, vb.x, wr0); fma4(ob, vb.y, wr1);
                fma4(ob, vb.z, wr2); fma4(ob, vb.w, wr3);
            }
        }
#pragma unroll
        for (int t = 0; t < 2; t++) {
            float* o = t ? ob : oa;
            float h0 = (o[0] > 0.f) ? o[0] : LEAKY * o[0];
            float h1 = (o[1] > 0.f) ? o[1] : LEAKY * o[1];
            float h2 = (o[2] > 0.f) ? o[2] : LEAKY * o[2];
            float h3 = (o[3] > 0.f) ? o[3] : LEAKY * o[3];
            float ss = h0 * h0 + h1 * h1 + h2 * h2 + h3 * h3;
            ss += __shfl_xor(ss, 1, 64);
            ss += __shfl_xor(ss, 2, 64);
            ss += __shfl_xor(ss, 4, 64);
            ss += __shfl_xor(ss, 8, 64);   // 16 lanes = one node
            float sc = 1.0f / fmaxf(sqrtf(ss), 1e-12f);
            int node = nb + 2 * gg + t;
            if (node < N) {
                float4 rv = {h0 * sc, h1 * sc, h2 * sc, h3 * sc};
                *(float4*)&out[(size_t)node * 64 + d0] = rv;
                Bf4 q = {__float2bfloat16(rv.x), __float2bfloat16(rv.y),
                         __float2bfloat16(rv.z), __float2bfloat16(rv.w)};
                *(Bf4*)&outb[(size_t)node * 64 + d0] = q;
            }
        }
    } else {
        int strip = lane & 7, nI = lane >> 3;    // 8 strips x 4 dims; 8 nodes
        int d0 = strip * 4;
        float4 b1v = *(const float4*)&b1[d0];
        float4 b2v = *(const float4*)&b2[d0];
        float o[4] = {b1v.x + b2v.x, b1v.y + b2v.y, b1v.z + b2v.z, b1v.w + b2v.w};
        const float* sp = &S[(wv * 8 + nI) * 132];
#pragma unroll
        for (int half = 0; half < 2; half++) {
            const float* W  = half ? W2 : W1;
            const float* sv = sp + half * 64;
#pragma unroll 2
            for (int k = 0; k < 64; k += 4) {
                float4 v   = *(const float4*)&sv[k];
                float4 wr0 = *(const float4*)&W[(k + 0) * 32 + d0];
                float4 wr1 = *(const float4*)&W[(k + 1) * 32 + d0];
                float4 wr2 = *(const float4*)&W[(k + 2) * 32 + d0];
                float4 wr3 = *(const float4*)&W[(k + 3) * 32 + d0];
                fma4(o, v.x, wr0); fma4(o, v.y, wr1);
                fma4(o, v.z, wr2); fma4(o, v.w, wr3);
            }
        }
        float h0 = (o[0] > 0.f) ? o[0] : LEAKY * o[0];
        float h1 = (o[1] > 0.f) ? o[1] : LEAKY * o[1];
        float h2 = (o[2] > 0.f) ? o[2] : LEAKY * o[2];
        float h3 = (o[3] > 0.f) ? o[3] : LEAKY * o[3];
        float ss = h0 * h0 + h1 * h1 + h2 * h2 + h3 * h3;
        ss += __shfl_xor(ss, 1, 64);
        ss += __shfl_xor(ss, 2, 64);
        ss += __shfl_xor(ss, 4, 64);       // 8 lanes = one node
        float sc = 1.0f / fmaxf(sqrtf(ss), 1e-12f);
        int node = nb + nI;
        if (node < N) {
            float4 rv = {h0 * sc, h1 * sc, h2 * sc, h3 * sc};
            *(float4*)&out[(size_t)node * 32 + d0] = rv;
        }
    }
}

// final = concat(a0, a1, a2); score[b] = dot(final[u], final[NU+i]) over 160 dims
__global__ __launch_bounds__(256) void score_pairs(
    const float* __restrict__ a0, const float* __restrict__ a1,
    const float* __restrict__ a2,
    const int* __restrict__ uid, const int* __restrict__ iid,
    float* __restrict__ out, int B, int NU) {
    int wave = threadIdx.x >> 6, lane = threadIdx.x & 63;
    int p = blockIdx.x * 4 + wave;
    if (p >= B) return;
    int u = uid[p], it = iid[p];
    size_t un = (size_t)u, in = (size_t)(NU + it);
    float s = a0[un * 64 + lane] * a0[in * 64 + lane];
    s = fmaf(a1[un * 64 + lane], a1[in * 64 + lane], s);
    if (lane < 32) s = fmaf(a2[un * 32 + lane], a2[in * 32 + lane], s);
#pragma unroll
    for (int m = 32; m >= 1; m >>= 1) s += __shfl_xor(s, m, 64);
    if (lane == 0) out[p] = s;
}

extern "C" void kernel_launch(void* const* d_in, const int* in_sizes, int n_in,
                              void* d_out, int out_size, void* d_ws, size_t ws_size,
                              hipStream_t stream) {
    const int*   edge_row  = (const int*)d_in[0];
    const int*   edge_col  = (const int*)d_in[1];
    const float* edge_vals = (const float*)d_in[2];
    const float* ue        = (const float*)d_in[3];
    const float* ee        = (const float*)d_in[4];
    const float* W1_0 = (const float*)d_in[5];
    const float* b1_0 = (const float*)d_in[6];
    const float* W2_0 = (const float*)d_in[7];
    const float* b2_0 = (const float*)d_in[8];
    const float* W1_1 = (const float*)d_in[9];
    const float* b1_1 = (const float*)d_in[10];
    const float* W2_1 = (const float*)d_in[11];
    const float* b2_1 = (const float*)d_in[12];
    const int*   uid  = (const int*)d_in[13];
    const int*   iid  = (const int*)d_in[14];
    float* out = (float*)d_out;

    const int E  = in_sizes[0];
    const int NU = in_sizes[3] / 64;
    const int NE = in_sizes[4] / 64;
    const int N  = NU + NE;
    const int B  = in_sizes[13];
    const int G  = (N + SCAN_TILE - 1) / SCAN_TILE;  // must be <= SCAN_BLOCK

    char* ws = (char*)d_ws;
    size_t off = 0;
    auto alloc = [&](size_t bytes) -> char* {
        char* p = ws + off;
        off = (off + bytes + 255) & ~(size_t)255;
        return p;
    };
    int*   deg      = (int*)alloc((size_t)N * 4);
    int*   row_ptr  = (int*)alloc((size_t)(N + 1) * 4);
    int*   cursor   = (int*)alloc((size_t)N * 4);
    int*   blocksum = (int*)alloc((size_t)1024 * 4);
    int2*  csr      = (int2*)alloc((size_t)E * 8);
    float* a0       = (float*)alloc((size_t)N * 64 * 4);
    float* a1       = (float*)alloc((size_t)N * 64 * 4);
    float* a2       = (float*)alloc((size_t)N * 32 * 4);
    __hip_bfloat16* a0b = (__hip_bfloat16*)alloc((size_t)N * 64 * 2);
    __hip_bfloat16* a1b = (__hip_bfloat16*)alloc((size_t)N * 64 * 2);
    (void)ws_size; (void)n_in; (void)out_size; (void)NE;

    int ntot4 = N * 16, nu4 = NU * 16;
    int GC = (E + 255) / 256;
    int GB = (ntot4 + 255) / 256;

    zero_i32<<<(N + 255) / 256, 256, 0, stream>>>(deg, N);
    count_and_build<<<GC + GB, 256, 0, stream>>>(edge_row, E, GC, deg,
                                                 (const float4*)ue, (const float4*)ee,
                                                 (float4*)a0, a0b, nu4, ntot4);
    scan_phase1<<<G, SCAN_BLOCK, 0, stream>>>(deg, blocksum, N);
    scan_phase3<<<G, SCAN_BLOCK, 0, stream>>>(deg, blocksum, row_ptr, cursor, G, N);
    fill_csr<<<GC, 256, 0, stream>>>(edge_row, edge_col, edge_vals, E, cursor, csr);
    gnn_layer<64><<<(N + 31) / 32, 256, 0, stream>>>(a0, a0b, csr, row_ptr,
                                                     W1_0, b1_0, W2_0, b2_0, a1, a1b, N);
    gnn_layer<32><<<(N + 31) / 32, 256, 0, stream>>>(a1, a1b, csr, row_ptr,
                                                     W1_1, b1_1, W2_1, b2_1, a2, nullptr, N);
    score_pairs<<<(B + 3) / 4, 256, 0, stream>>>(a0, a1, a2, uid, iid, out, B, NU);
}